// Round 7
// baseline (43.282 us; speedup 1.0000x reference)
//
#include <hip/hip_runtime.h>

// GraphSearchPolicy fused kernel, score-all-relations, BB=8, 1024 threads.
// MI355X gfx950. B=2048, A=256, DE=128, DH=256, DR=128, DIN=512, ACT=256, NR=1000.
//
// Grid 256 blocks x 1024 threads = 16 waves/block = 1 block/CU, 4 waves/SIMD.
// Same L2 traffic as BB=8/512thr (W1 512KB + W2 128KB + rel_embT 512KB per
// block ~ 300MB total) but 2x the latency-hiding depth in every phase.

#define DE   128
#define DH   256
#define DR   128
#define DIN  512
#define ACT  256
#define AA   256
#define BB   8
#define NR   1000

// ---------------------------------------------------------------- transpose
// LDS-tiled: 125 blocks x 1024 thr, 8 rel rows per block.
__global__ __launch_bounds__(1024) void transpose_kernel(
    const float* __restrict__ rel_emb, float* __restrict__ rel_embT)
{
    __shared__ float ldsT[128 * 9];      // [k][row], pad 9 -> conflict-free
    const int t  = threadIdx.x;
    const int r0 = blockIdx.x * 8;
    {
        const int row = t >> 7;          // 0..7
        const int k   = t & 127;
        ldsT[k * 9 + row] = rel_emb[(size_t)(r0 + row) * DR + k];
    }
    __syncthreads();
    {
        const int k = t >> 3;            // 0..127
        const int j = t & 7;
        rel_embT[(size_t)k * NR + r0 + j] = ldsT[k * 9 + j];
    }
}

// ---------------------------------------------------------------- main
__global__ __launch_bounds__(1024, 4) void policy_kernel(
    const int*   __restrict__ e,
    const int*   __restrict__ q,
    const float* __restrict__ H,
    const int*   __restrict__ r_space,
    const float* __restrict__ r_mask,
    const float* __restrict__ entity_emb,
    const float* __restrict__ rel_emb,
    const float* __restrict__ W1,
    const float* __restrict__ b1,
    const float* __restrict__ W2,
    const float* __restrict__ b2,
    const float* __restrict__ rel_embT,
    float* __restrict__ dist_out,
    float* __restrict__ ent_out)
{
    const int t  = threadIdx.x;          // 0..1023
    const int b0 = blockIdx.x * BB;

    __shared__ __align__(16) float xvT[DIN * BB];      // [k][row]   16 KB
    __shared__ __align__(16) float part[8 * BB * ACT]; // partials   64 KB (reused)
    __shared__ __align__(16) float hs[BB][ACT];        // [row][col]  8 KB
    __shared__ __align__(16) float x2s[BB][DR];        // [row][col]  4 KB
    __shared__ float scoreL[BB * NR];                  // 31.25 KB
    __shared__ float wredM[16][2], wredS[16][2], wredL[16][2];

    // ---- early loads: action indices + masks (latency hides under MLP) ----
    const int a  = t & 255;              // action
    const int rp = t >> 8;               // 0..3 -> rows {2rp, 2rp+1}
    const int rA = 2 * rp, rB = rA + 1;
    const int   ridx0 = r_space[(size_t)(b0 + rA) * AA + a];
    const int   ridx1 = r_space[(size_t)(b0 + rB) * AA + a];
    const float msk0  = r_mask [(size_t)(b0 + rA) * AA + a];
    const float msk1  = r_mask [(size_t)(b0 + rB) * AA + a];

    // ---- stage X = concat(E,H,Q) into xvT[k][row], LDS-consecutive rounds ----
    {
        const int srow = t & 7;
        const int scol = t >> 3;         // 0..127
        const int sb   = b0 + srow;
        const int eb   = e[sb];
        const int qb   = q[sb];
        #pragma unroll
        for (int rnd = 0; rnd < 4; ++rnd) {
            const int k = rnd * 128 + scol;
            float v;
            if (k < DE)            v = entity_emb[(size_t)eb * DE + k];
            else if (k < DE + DH)  v = H[(size_t)sb * DH + (k - DE)];
            else                   v = rel_emb[(size_t)qb * DR + (k - DE - DH)];
            xvT[k * BB + srow] = v;      // addr = rnd*1024 + t : consecutive
        }
    }
    __syncthreads();

    // ---- layer 1 partials: 8 k-slices x (128 thr -> 2 cols each) ----
    {
        const int ks   = t >> 7;         // 0..7, owns k in [ks*64, +64)
        const int col2 = (t & 127) * 2;
        float2 acc[8];
        #pragma unroll
        for (int j = 0; j < 8; ++j) acc[j] = make_float2(0.f, 0.f);
        const float* wbase = &W1[(size_t)(ks * 64) * ACT + col2];
        const float* xbase = &xvT[(ks * 64) * BB];
        #pragma unroll 8
        for (int kk = 0; kk < 64; ++kk) {
            const float2 w  = *(const float2*)(wbase + (size_t)kk * ACT); // 512B/wave
            const float4 xa = *(const float4*)(xbase + kk * BB);          // bcast rows 0-3
            const float4 xb = *(const float4*)(xbase + kk * BB + 4);      // bcast rows 4-7
            const float xj[8] = {xa.x, xa.y, xa.z, xa.w, xb.x, xb.y, xb.z, xb.w};
            #pragma unroll
            for (int j = 0; j < 8; ++j) {
                acc[j].x = fmaf(w.x, xj[j], acc[j].x);
                acc[j].y = fmaf(w.y, xj[j], acc[j].y);
            }
        }
        float* pb = &part[(size_t)(ks * BB) * ACT + col2];
        #pragma unroll
        for (int j = 0; j < 8; ++j)
            *(float2*)(pb + (size_t)j * ACT) = acc[j];   // 512B/wave consecutive
    }
    __syncthreads();

    // ---- combine1 + bias + ReLU -> hs[row][col] ----
    #pragma unroll
    for (int i = 0; i < 2; ++i) {
        const int o   = t + i * 1024;    // 0..2047
        const int row = o >> 8;
        const int col = o & 255;
        float s = b1[col];
        #pragma unroll
        for (int ks = 0; ks < 8; ++ks)
            s += part[(ks * BB + row) * ACT + col];      // consecutive col
        hs[row][col] = fmaxf(s, 0.f);
    }
    __syncthreads();

    // ---- layer 2 partials: 8 k-slices x (128 thr -> 1 col each) ----
    {
        const int ks2 = t >> 7;          // owns k in [ks2*32, +32)
        const int col = t & 127;
        const int k0  = ks2 * 32;
        float acc[8];
        #pragma unroll
        for (int j = 0; j < 8; ++j) acc[j] = 0.f;
        #pragma unroll 2
        for (int k4 = 0; k4 < 32; k4 += 4) {
            float4 hr[8];
            #pragma unroll
            for (int j = 0; j < 8; ++j)
                hr[j] = *(const float4*)&hs[j][k0 + k4]; // b128 broadcast
            #define L2_STEP(COMP, KOFF)                                        \
            {                                                                  \
                const float w = W2[(size_t)(k0 + k4 + KOFF) * DR + col];       \
                _Pragma("unroll")                                              \
                for (int j = 0; j < 8; ++j)                                    \
                    acc[j] = fmaf(w, hr[j].COMP, acc[j]);                      \
            }
            L2_STEP(x, 0) L2_STEP(y, 1) L2_STEP(z, 2) L2_STEP(w, 3)
            #undef L2_STEP
        }
        float* pb = &part[(size_t)(ks2 * BB) * DR + col];
        #pragma unroll
        for (int j = 0; j < 8; ++j)
            pb[(size_t)j * DR] = acc[j];                 // 256B/wave consecutive
    }
    __syncthreads();

    // ---- combine2 + bias -> x2s[row][col] (1 output/thread) ----
    {
        const int row = t >> 7;
        const int col = t & 127;
        float s = b2[col];
        #pragma unroll
        for (int ks = 0; ks < 8; ++ks)
            s += part[(ks * BB + row) * DR + col];
        x2s[row][col] = s;
    }
    __syncthreads();

    // ---- score GEMM: scoreL[row][r] = sum_k x2s[row][k]*rel_embT[k][r] ----
    {
        const bool valid = (t < NR);
        const int  r     = valid ? t : (NR - 1);
        float acc[8];
        #pragma unroll
        for (int j = 0; j < 8; ++j) acc[j] = 0.f;
        #pragma unroll 4
        for (int k4 = 0; k4 < DR; k4 += 4) {
            float4 xr[8];
            #pragma unroll
            for (int j = 0; j < 8; ++j)
                xr[j] = *(const float4*)&x2s[j][k4];     // b128 broadcast
            #define SC_STEP(COMP, KOFF)                                        \
            {                                                                  \
                const float w = rel_embT[(size_t)(k4 + KOFF) * NR + r];        \
                _Pragma("unroll")                                              \
                for (int j = 0; j < 8; ++j)                                    \
                    acc[j] = fmaf(w, xr[j].COMP, acc[j]);                      \
            }
            SC_STEP(x, 0) SC_STEP(y, 1) SC_STEP(z, 2) SC_STEP(w, 3)
            #undef SC_STEP
        }
        if (valid) {
            #pragma unroll
            for (int j = 0; j < 8; ++j) scoreL[j * NR + t] = acc[j];
        }
    }
    __syncthreads();

    // ---- logits: 4-byte LDS lookups for this thread's 2 rows ----
    const float lg0 = scoreL[rA * NR + ridx0] - (1.0f - msk0) * 1e31f;
    const float lg1 = scoreL[rB * NR + ridx1] - (1.0f - msk1) * 1e31f;

    const int wv = t >> 6;               // 0..15; waves [rp*4, rp*4+4) share rows

    // ---- max ----
    float m0 = lg0, m1 = lg1;
    #pragma unroll
    for (int off = 32; off >= 1; off >>= 1) {
        m0 = fmaxf(m0, __shfl_xor(m0, off, 64));
        m1 = fmaxf(m1, __shfl_xor(m1, off, 64));
    }
    if ((t & 63) == 0) { wredM[wv][0] = m0; wredM[wv][1] = m1; }
    __syncthreads();
    {
        const int wb = rp * 4;
        m0 = fmaxf(fmaxf(wredM[wb][0], wredM[wb+1][0]), fmaxf(wredM[wb+2][0], wredM[wb+3][0]));
        m1 = fmaxf(fmaxf(wredM[wb][1], wredM[wb+1][1]), fmaxf(wredM[wb+2][1], wredM[wb+3][1]));
    }

    // ---- exp + joint sums S, SL = sum p*(lg-m) ----
    const float z0 = lg0 - m0, z1 = lg1 - m1;
    const float p0 = __expf(z0), p1 = __expf(z1);
    float s0 = p0, s1 = p1, sl0 = p0 * z0, sl1 = p1 * z1;
    #pragma unroll
    for (int off = 32; off >= 1; off >>= 1) {
        s0  += __shfl_xor(s0,  off, 64);
        s1  += __shfl_xor(s1,  off, 64);
        sl0 += __shfl_xor(sl0, off, 64);
        sl1 += __shfl_xor(sl1, off, 64);
    }
    if ((t & 63) == 0) {
        wredS[wv][0] = s0;  wredS[wv][1] = s1;
        wredL[wv][0] = sl0; wredL[wv][1] = sl1;
    }
    __syncthreads();
    float S0, S1, SL0, SL1;
    {
        const int wb = rp * 4;
        S0  = wredS[wb][0] + wredS[wb+1][0] + wredS[wb+2][0] + wredS[wb+3][0];
        S1  = wredS[wb][1] + wredS[wb+1][1] + wredS[wb+2][1] + wredS[wb+3][1];
        SL0 = wredL[wb][0] + wredL[wb+1][0] + wredL[wb+2][0] + wredL[wb+3][0];
        SL1 = wredL[wb][1] + wredL[wb+1][1] + wredL[wb+2][1] + wredL[wb+3][1];
    }

    // ---- outputs ----
    dist_out[(size_t)(b0 + rA) * AA + a] = p0 / S0;
    dist_out[(size_t)(b0 + rB) * AA + a] = p1 / S1;
    if ((t & 255) == 0) {                // t = 0,256,512,768 -> rp = 0..3
        ent_out[b0 + rA] = __logf(S0) - SL0 / S0;
        ent_out[b0 + rB] = __logf(S1) - SL1 / S1;
    }
}

extern "C" void kernel_launch(void* const* d_in, const int* in_sizes, int n_in,
                              void* d_out, int out_size, void* d_ws, size_t ws_size,
                              hipStream_t stream) {
    const int*   e          = (const int*)  d_in[0];
    const int*   q          = (const int*)  d_in[1];
    const float* H          = (const float*)d_in[2];
    const int*   r_space    = (const int*)  d_in[3];
    const float* r_mask     = (const float*)d_in[4];
    const float* entity_emb = (const float*)d_in[5];
    const float* rel_emb    = (const float*)d_in[6];
    const float* W1         = (const float*)d_in[7];
    const float* b1         = (const float*)d_in[8];
    const float* W2         = (const float*)d_in[9];
    const float* b2         = (const float*)d_in[10];

    const int B = in_sizes[0];              // 2048
    float* dist_out = (float*)d_out;                    // [B, 256]
    float* ent_out  = (float*)d_out + (size_t)B * AA;   // [B]
    float* rel_embT = (float*)d_ws;                     // [128][1000] = 512 KB

    transpose_kernel<<<NR / 8, 1024, 0, stream>>>(rel_emb, rel_embT);
    policy_kernel<<<B / BB, 1024, 0, stream>>>(
        e, q, H, r_space, r_mask, entity_emb, rel_emb,
        W1, b1, W2, b2, rel_embT, dist_out, ent_out);
}